// Round 13
// baseline (545.465 us; speedup 1.0000x reference)
//
#include <hip/hip_runtime.h>

// ---------------------------------------------------------------------------
// TransformerBlock: out = LN( FFN(X) + X ),  X = LN( Q + softmax(QK^T/s) V )
// B=32, SQ=SK=D=1024.  bf16 MFMA GEMMs (fp32 accum, 256^2 8-phase schedule),
// LDS-vectorized bf16 epilogues with fused bias/residual, fp32 softmax/LN.
// Cast kernel: 8-deep asm load batch + fully-coalesced 16B u16x8 stores.
// ---------------------------------------------------------------------------

typedef __attribute__((ext_vector_type(8))) short bf16x8;
typedef __attribute__((ext_vector_type(8))) unsigned short u16x8;
typedef __attribute__((ext_vector_type(4))) float f32x4;

__device__ __forceinline__ unsigned short f2bf(float f) {
  union { float f; unsigned u; } x; x.f = f;
  unsigned r = x.u + 0x7fffu + ((x.u >> 16) & 1u);  // round-to-nearest-even
  return (unsigned short)(r >> 16);
}
__device__ __forceinline__ float bf2f(unsigned short u) {
  union { unsigned u; float f; } x; x.u = (unsigned)u << 16;
  return x.f;
}

// ---------------- fused cast f32 -> bf16 for Q, K, W1, W2 -------------------
// blocks: [0,1024) Q, [1024,2048) K, [2048,2080) W1, [2080,2112) W2.
// Lane j-chunk: two float4 loads 32B-stride pair -> one u16x8 (16B) store,
// lane-contiguous (1KB/wave per store instr). 8 loads batched via inline asm.
__global__ __launch_bounds__(256) void cast_all_kernel(
    const float* __restrict__ Q, const float* __restrict__ K,
    const float* __restrict__ W1, const float* __restrict__ W2,
    unsigned short* __restrict__ Qb, unsigned short* __restrict__ Kb,
    unsigned short* __restrict__ W1b, unsigned short* __restrict__ W2b) {
  const float* src; unsigned short* dst; long base;
  const int b = blockIdx.x;
  if (b < 1024)      { src = Q;  dst = Qb;  base = (long)b * 32768; }
  else if (b < 2048) { src = K;  dst = Kb;  base = (long)(b - 1024) * 32768; }
  else if (b < 2080) { src = W1; dst = W1b; base = (long)(b - 2048) * 32768; }
  else               { src = W2; dst = W2b; base = (long)(b - 2080) * 32768; }
  const int t = threadIdx.x;
#pragma unroll
  for (int it = 0; it < 4; ++it) {
    const long e0 = base + it * 8192 + t * 8;  // lane-contiguous 8-float span
    const float* p0 = src + e0;
    const float* p1 = src + e0 + 2048;
    const float* p2 = src + e0 + 4096;
    const float* p3 = src + e0 + 6144;
    f32x4 a0, b0, a1, b1, a2, b2, a3, b3;
    asm volatile("global_load_dwordx4 %0, %1, off" : "=v"(a0) : "v"(p0) : "memory");
    asm volatile("global_load_dwordx4 %0, %1, off offset:16" : "=v"(b0) : "v"(p0) : "memory");
    asm volatile("global_load_dwordx4 %0, %1, off" : "=v"(a1) : "v"(p1) : "memory");
    asm volatile("global_load_dwordx4 %0, %1, off offset:16" : "=v"(b1) : "v"(p1) : "memory");
    asm volatile("global_load_dwordx4 %0, %1, off" : "=v"(a2) : "v"(p2) : "memory");
    asm volatile("global_load_dwordx4 %0, %1, off offset:16" : "=v"(b2) : "v"(p2) : "memory");
    asm volatile("global_load_dwordx4 %0, %1, off" : "=v"(a3) : "v"(p3) : "memory");
    asm volatile("global_load_dwordx4 %0, %1, off offset:16" : "=v"(b3) : "v"(p3) : "memory");
    asm volatile("s_waitcnt vmcnt(0)" ::: "memory");
    __builtin_amdgcn_sched_barrier(0);
    u16x8 o;
    o[0] = f2bf(a0[0]); o[1] = f2bf(a0[1]); o[2] = f2bf(a0[2]); o[3] = f2bf(a0[3]);
    o[4] = f2bf(b0[0]); o[5] = f2bf(b0[1]); o[6] = f2bf(b0[2]); o[7] = f2bf(b0[3]);
    *(u16x8*)(dst + e0) = o;
    o[0] = f2bf(a1[0]); o[1] = f2bf(a1[1]); o[2] = f2bf(a1[2]); o[3] = f2bf(a1[3]);
    o[4] = f2bf(b1[0]); o[5] = f2bf(b1[1]); o[6] = f2bf(b1[2]); o[7] = f2bf(b1[3]);
    *(u16x8*)(dst + e0 + 2048) = o;
    o[0] = f2bf(a2[0]); o[1] = f2bf(a2[1]); o[2] = f2bf(a2[2]); o[3] = f2bf(a2[3]);
    o[4] = f2bf(b2[0]); o[5] = f2bf(b2[1]); o[6] = f2bf(b2[2]); o[7] = f2bf(b2[3]);
    *(u16x8*)(dst + e0 + 4096) = o;
    o[0] = f2bf(a3[0]); o[1] = f2bf(a3[1]); o[2] = f2bf(a3[2]); o[3] = f2bf(a3[3]);
    o[4] = f2bf(b3[0]); o[5] = f2bf(b3[1]); o[6] = f2bf(b3[2]); o[7] = f2bf(b3[3]);
    *(u16x8*)(dst + e0 + 6144) = o;
  }
}

// -------- per-batch transpose + cast: Vt[b][d][k] = bf16(V[b][k][d]) --------
__global__ __launch_bounds__(256) void transpose_cast_kernel(const float* __restrict__ V,
                                                             unsigned short* __restrict__ Vt) {
  __shared__ float tile[64][65];
  const int b = blockIdx.z;
  const float* Vb = V + (size_t)b * 1024 * 1024;
  unsigned short* Vtb = Vt + (size_t)b * 1024 * 1024;
  const int d0 = blockIdx.x * 64, k0 = blockIdx.y * 64;
  const int tc = (threadIdx.x & 15) * 4;
  const int tr = threadIdx.x >> 4;
  float4 v0 = *(const float4*)&Vb[(size_t)(k0 + tr) * 1024 + d0 + tc];
  float4 v1 = *(const float4*)&Vb[(size_t)(k0 + tr + 16) * 1024 + d0 + tc];
  float4 v2 = *(const float4*)&Vb[(size_t)(k0 + tr + 32) * 1024 + d0 + tc];
  float4 v3 = *(const float4*)&Vb[(size_t)(k0 + tr + 48) * 1024 + d0 + tc];
  __builtin_amdgcn_sched_barrier(0);
  tile[tr][tc] = v0.x; tile[tr][tc + 1] = v0.y; tile[tr][tc + 2] = v0.z; tile[tr][tc + 3] = v0.w;
  tile[tr + 16][tc] = v1.x; tile[tr + 16][tc + 1] = v1.y; tile[tr + 16][tc + 2] = v1.z; tile[tr + 16][tc + 3] = v1.w;
  tile[tr + 32][tc] = v2.x; tile[tr + 32][tc + 1] = v2.y; tile[tr + 32][tc + 2] = v2.z; tile[tr + 32][tc + 3] = v2.w;
  tile[tr + 48][tc] = v3.x; tile[tr + 48][tc + 1] = v3.y; tile[tr + 48][tc + 2] = v3.z; tile[tr + 48][tc + 3] = v3.w;
  __syncthreads();
  const int dr = threadIdx.x >> 2;
  const int k4 = (threadIdx.x & 3) * 16;
  u16x8 o0, o1;
#pragma unroll
  for (int j = 0; j < 8; ++j) o0[j] = f2bf(tile[k4 + j][dr]);
#pragma unroll
  for (int j = 0; j < 8; ++j) o1[j] = f2bf(tile[k4 + 8 + j][dr]);
  unsigned short* outp = &Vtb[(size_t)(d0 + dr) * 1024 + k0 + k4];
  *(u16x8*)outp = o0;
  *(u16x8*)(outp + 8) = o1;
}

// ---------------------------------------------------------------------------
// GEMM: C_bf16 = epi(A @ B^T)  (A:[M][K], B:[N][K] row-major bf16)
// 256x256 tile, BK=64, 8 waves (2Mx4N), 8-phase schedule, counted vmcnt(4),
// T2 XOR-swizzle both-sides, T5 setprio, T1 XCD swizzle, LDS-staged epilogue.
// EPI: 4 = acc*scale ; 6 = acc+resb ; 2 = relu(acc+bias) ; 7 = acc+bias+resb
// ---------------------------------------------------------------------------
template <int EPI>
__global__ __launch_bounds__(512, 2) void gemm8(
    const unsigned short* __restrict__ A, const unsigned short* __restrict__ B,
    const float* __restrict__ bias, const unsigned short* __restrict__ resb,
    unsigned short* __restrict__ Cout,
    int N, int K, long sA, long sB, long sC, float scale, int gx, int gxy) {

  __shared__ char smem[131072];

  const int nwg = gridDim.x;
  const int orig = blockIdx.x;
  const int wg = (orig & 7) * (nwg >> 3) + (orig >> 3);
  const int bz = wg / gxy;
  const int rem = wg - bz * gxy;
  const int by = rem / gx;
  const int bx = rem - by * gx;

  A += (size_t)bz * sA;
  B += (size_t)bz * sB;
  const size_t cbase = (size_t)bz * sC;
  const int brow = by * 256, bcol = bx * 256;

  const int tid = threadIdx.x;
  const int wave = tid >> 6, lane = tid & 63;
  const int wm = wave >> 2, wn = wave & 3;
  const int lr = lane & 15, kh = lane >> 4;
  const int swz = (lane & 7) << 4;

  const int s_r = wave * 8 + (lane >> 3);
  const int s_c = ((lane & 7) ^ (lane >> 3)) * 8;

  auto stg = [&](const unsigned short* g, int rowbase, int kt, int h, int mat) {
    char* region = smem + mat * 65536 + (kt & 1) * 32768;
#pragma unroll
    for (int j = 0; j < 2; ++j) {
      const unsigned short* src =
          g + (size_t)(rowbase + h * 128 + j * 64 + s_r) * K + kt * 64 + s_c;
      char* dst = region + h * 16384 + j * 8192 + wave * 1024;
      __builtin_amdgcn_global_load_lds(
          (const __attribute__((address_space(1))) void*)src,
          (__attribute__((address_space(3))) void*)dst, 16, 0, 0);
    }
  };

  auto rdA = [&](int c, int m, int k) -> bf16x8 {
    const int r = wm * 128 + m * 16 + lr;
    const int off = r * 128 + ((k * 64 + kh * 16) ^ swz);
    return *(const bf16x8*)(smem + c * 32768 + off);
  };
  auto rdB = [&](int c, int n, int k) -> bf16x8 {
    const int r = wn * 64 + n * 16 + lr;
    const int off = r * 128 + ((k * 64 + kh * 16) ^ swz);
    return *(const bf16x8*)(smem + 65536 + c * 32768 + off);
  };

  f32x4 acc[8][4];
#pragma unroll
  for (int m = 0; m < 8; ++m)
#pragma unroll
    for (int n = 0; n < 4; ++n)
#pragma unroll
      for (int i = 0; i < 4; ++i) acc[m][n][i] = 0.f;

  const int nkt = K >> 6;
  const int nI = nkt >> 1;

  stg(A, brow, 0, 0, 0); stg(A, brow, 0, 1, 0);
  stg(B, bcol, 0, 0, 1); stg(B, bcol, 0, 1, 1);
  stg(B, bcol, 1, 0, 1); stg(B, bcol, 1, 1, 1);
  stg(A, brow, 1, 0, 0); stg(A, brow, 1, 1, 0);
  asm volatile("s_waitcnt vmcnt(8)" ::: "memory");
  asm volatile("s_barrier" ::: "memory");

  bf16x8 bfrag[4][2];

  for (int I = 0; I < nI; ++I) {
    const bool nl = (I + 1 < nI);
#pragma unroll
    for (int g = 0; g < 2; ++g) {
#pragma unroll
      for (int q = 0; q < 4; ++q) {
        const int p = g * 4 + q;

        if (q == 0) {
#pragma unroll
          for (int n = 0; n < 4; ++n)
#pragma unroll
            for (int k = 0; k < 2; ++k) bfrag[n][k] = rdB(g, n, k);
        }
        bf16x8 afr[2][2];
#pragma unroll
        for (int mm = 0; mm < 2; ++mm)
#pragma unroll
          for (int k = 0; k < 2; ++k) afr[mm][k] = rdA(g, q * 2 + mm, k);

        if (p == 0) { if (I > 0) stg(A, brow, 2 * I + 1, 0, 0); }
        if (p == 1) { if (I > 0) stg(A, brow, 2 * I + 1, 1, 0);
                      if (nl) stg(B, bcol, 2 * I + 2, 0, 1); }
        if (p == 2) { if (nl) stg(B, bcol, 2 * I + 2, 1, 1); }
        if (p == 4) { if (nl) stg(A, brow, 2 * I + 2, 0, 0); }
        if (p == 5) { if (nl) { stg(A, brow, 2 * I + 2, 1, 0);
                                stg(B, bcol, 2 * I + 3, 0, 1); } }
        if (p == 6) { if (nl) stg(B, bcol, 2 * I + 3, 1, 1); }

        if (q == 0) asm volatile("s_waitcnt lgkmcnt(8)" ::: "memory");
        asm volatile("s_barrier" ::: "memory");

        __builtin_amdgcn_s_setprio(1);
#pragma unroll
        for (int k = 0; k < 2; ++k)
#pragma unroll
          for (int mm = 0; mm < 2; ++mm)
#pragma unroll
            for (int n = 0; n < 4; ++n)
              acc[q * 2 + mm][n] = __builtin_amdgcn_mfma_f32_16x16x32_bf16(
                  afr[mm][k], bfrag[n][k], acc[q * 2 + mm][n], 0, 0, 0);
        __builtin_amdgcn_s_setprio(0);

        if (q == 3) {
          if (g == 0 && !nl) asm volatile("s_waitcnt vmcnt(0)" ::: "memory");
          else               asm volatile("s_waitcnt vmcnt(4)" ::: "memory");
        }
        asm volatile("s_barrier" ::: "memory");
      }
    }
  }

  float* eplds = (float*)smem;
#pragma unroll
  for (int pass = 0; pass < 2; ++pass) {
    __syncthreads();
    if (wm == pass) {
#pragma unroll
      for (int m = 0; m < 8; ++m)
#pragma unroll
        for (int n = 0; n < 4; ++n)
#pragma unroll
          for (int i = 0; i < 4; ++i) {
            const int r = m * 16 + kh * 4 + i;
            const int c = wn * 64 + n * 16 + lr;
            eplds[r * 256 + (c ^ ((r & 7) << 2))] = acc[m][n][i];
          }
    }
    __syncthreads();
#pragma unroll
    for (int j = 0; j < 16; ++j) {
      const int rl = j * 8 + wave;
      const int grow = brow + pass * 128 + rl;
      const int gcol = bcol + lane * 4;
      const size_t idx = cbase + (size_t)grow * N + gcol;
      float4 v = *(const float4*)&eplds[rl * 256 + ((lane * 4) ^ ((rl & 7) << 2))];
      float o0 = v.x, o1 = v.y, o2 = v.z, o3 = v.w;
      if (EPI == 4) {
        o0 *= scale; o1 *= scale; o2 *= scale; o3 *= scale;
      } else if (EPI == 6) {
        ushort4 r = *(const ushort4*)&resb[idx];
        o0 += bf2f(r.x); o1 += bf2f(r.y); o2 += bf2f(r.z); o3 += bf2f(r.w);
      } else if (EPI == 2) {
        float4 bb = *(const float4*)&bias[gcol];
        o0 = fmaxf(o0 + bb.x, 0.f); o1 = fmaxf(o1 + bb.y, 0.f);
        o2 = fmaxf(o2 + bb.z, 0.f); o3 = fmaxf(o3 + bb.w, 0.f);
      } else {  // EPI == 7
        float4 bb = *(const float4*)&bias[gcol];
        ushort4 r = *(const ushort4*)&resb[idx];
        o0 += bb.x + bf2f(r.x); o1 += bb.y + bf2f(r.y);
        o2 += bb.z + bf2f(r.z); o3 += bb.w + bf2f(r.w);
      }
      ushort4 o;
      o.x = f2bf(o0); o.y = f2bf(o1); o.z = f2bf(o2); o.w = f2bf(o3);
      *(ushort4*)&Cout[idx] = o;
    }
  }
}

// ---------------- row softmax (in-place bf16): P = softmax(S) ---------------
__global__ __launch_bounds__(256) void softmax_kernel(unsigned short* __restrict__ S) {
  __shared__ float red[4];
  const size_t row = blockIdx.x;
  const int t = threadIdx.x;
  ushort4 u = *(const ushort4*)(S + row * 1024 + t * 4);
  float v0 = bf2f(u.x), v1 = bf2f(u.y), v2 = bf2f(u.z), v3 = bf2f(u.w);
  float mx = fmaxf(fmaxf(v0, v1), fmaxf(v2, v3));
#pragma unroll
  for (int o = 32; o; o >>= 1) mx = fmaxf(mx, __shfl_xor(mx, o));
  if ((t & 63) == 0) red[t >> 6] = mx;
  __syncthreads();
  mx = fmaxf(fmaxf(red[0], red[1]), fmaxf(red[2], red[3]));
  __syncthreads();
  float e0 = __expf(v0 - mx), e1 = __expf(v1 - mx);
  float e2 = __expf(v2 - mx), e3 = __expf(v3 - mx);
  float s = e0 + e1 + e2 + e3;
#pragma unroll
  for (int o = 32; o; o >>= 1) s += __shfl_xor(s, o);
  if ((t & 63) == 0) red[t >> 6] = s;
  __syncthreads();
  s = red[0] + red[1] + red[2] + red[3];
  const float inv = 1.f / s;
  ushort4 o4;
  o4.x = f2bf(e0 * inv); o4.y = f2bf(e1 * inv);
  o4.z = f2bf(e2 * inv); o4.w = f2bf(e3 * inv);
  *(ushort4*)(S + row * 1024 + t * 4) = o4;
}

// ---------------- LayerNorm over rows of 1024, bf16 input -------------------
__global__ __launch_bounds__(256) void ln_bf_kernel(
    const unsigned short* __restrict__ A,
    const float* __restrict__ gamma, const float* __restrict__ beta,
    float* __restrict__ Xf, unsigned short* __restrict__ Xb) {
  __shared__ float red[4];
  const size_t row = blockIdx.x;
  const int t = threadIdx.x;
  ushort4 ua = *(const ushort4*)(A + row * 1024 + t * 4);
  float x0 = bf2f(ua.x), x1 = bf2f(ua.y), x2 = bf2f(ua.z), x3 = bf2f(ua.w);
  float s = x0 + x1 + x2 + x3;
  float q = x0 * x0 + x1 * x1 + x2 * x2 + x3 * x3;
#pragma unroll
  for (int o = 32; o; o >>= 1) { s += __shfl_xor(s, o); q += __shfl_xor(q, o); }
  if ((t & 63) == 0) red[t >> 6] = s;
  __syncthreads();
  s = red[0] + red[1] + red[2] + red[3];
  __syncthreads();
  if ((t & 63) == 0) red[t >> 6] = q;
  __syncthreads();
  q = red[0] + red[1] + red[2] + red[3];
  const float mu = s * (1.f / 1024.f);
  const float var = q * (1.f / 1024.f) - mu * mu;
  const float rs = rsqrtf(var + 1e-5f);
  float4 g = *(const float4*)(gamma + t * 4);
  float4 be = *(const float4*)(beta + t * 4);
  float o0 = (x0 - mu) * rs * g.x + be.x;
  float o1 = (x1 - mu) * rs * g.y + be.y;
  float o2 = (x2 - mu) * rs * g.z + be.z;
  float o3 = (x3 - mu) * rs * g.w + be.w;
  if (Xf) {
    float4 o; o.x = o0; o.y = o1; o.z = o2; o.w = o3;
    *(float4*)(Xf + row * 1024 + t * 4) = o;
  }
  if (Xb) {
    ushort4 u; u.x = f2bf(o0); u.y = f2bf(o1); u.z = f2bf(o2); u.w = f2bf(o3);
    *(ushort4*)(Xb + row * 1024 + t * 4) = u;
  }
}

// ---------------------------------------------------------------------------
extern "C" void kernel_launch(void* const* d_in, const int* in_sizes, int n_in,
                              void* d_out, int out_size, void* d_ws, size_t ws_size,
                              hipStream_t stream) {
  const float* Q    = (const float*)d_in[0];
  const float* Km   = (const float*)d_in[1];
  const float* V    = (const float*)d_in[2];
  const float* W1   = (const float*)d_in[3];
  const float* b1   = (const float*)d_in[4];
  const float* W2   = (const float*)d_in[5];
  const float* b2   = (const float*)d_in[6];
  const float* gamma = (const float*)d_in[7];
  const float* beta  = (const float*)d_in[8];
  float* out = (float*)d_out;

  // workspace (bf16 planes of 64MB = 32M elements):
  //  Qb, Kb, Vtb, Sb(->P, ->Hb), VAb(->Fb), Xb, W1b, W2b
  char* ws = (char*)d_ws;
  const size_t NEL = (size_t)32 * 1024 * 1024;
  unsigned short* Qb  = (unsigned short*)ws;
  unsigned short* Kb  = Qb + NEL;
  unsigned short* Vtb = Kb + NEL;
  unsigned short* Sb  = Vtb + NEL;
  unsigned short* VAb = Sb + NEL;
  unsigned short* Xb  = VAb + NEL;
  unsigned short* W1b = Xb + NEL;
  unsigned short* W2b = W1b + 1024 * 1024;
  unsigned short* Hb  = Sb;    // alias: P dead after GEMM2
  unsigned short* Fb  = VAb;   // alias: VAb dead after ln1

  const long M1 = 1024L * 1024L;
  const float scale = 1.0f / (sqrtf(1024.0f) + 1e-8f);

  cast_all_kernel<<<2112, 256, 0, stream>>>(Q, Km, W1, W2, Qb, Kb, W1b, W2b);
  transpose_cast_kernel<<<dim3(16, 16, 32), 256, 0, stream>>>(V, Vtb);

  // Sb = bf16((Q K^T) * scale)    [grid 4x4x32 = 512]
  gemm8<4><<<512, 512, 0, stream>>>(Qb, Kb, nullptr, nullptr, Sb,
                                    1024, 1024, M1, M1, M1, scale, 4, 16);
  softmax_kernel<<<32768, 256, 0, stream>>>(Sb);
  // VAb = bf16(P @ Vt^T + Qb)     (residual fused, bf16)
  gemm8<6><<<512, 512, 0, stream>>>(Sb, Vtb, nullptr, Qb, VAb,
                                    1024, 1024, M1, M1, M1, 1.0f, 4, 16);
  // Xb = bf16(LN(VAb))
  ln_bf_kernel<<<32768, 256, 0, stream>>>(VAb, gamma, beta, nullptr, Xb);
  // Hb = bf16(relu(Xb @ W1^T + b1))   [M=32768: grid 4x128]
  gemm8<2><<<512, 512, 0, stream>>>(Xb, W1b, b1, nullptr, Hb,
                                    1024, 1024, 0, 0, 0, 1.0f, 4, 512);
  // Fb = bf16(Hb @ W2^T + b2 + Xb)    (residual fused)
  gemm8<7><<<512, 512, 0, stream>>>(Hb, W2b, b2, Xb, Fb,
                                    1024, 1024, 0, 0, 0, 1.0f, 4, 512);
  // out = LN(Fb)  (fp32 final)
  ln_bf_kernel<<<32768, 256, 0, stream>>>(Fb, gamma, beta, out, nullptr);
}

// Round 14
// 517.127 us; speedup vs baseline: 1.0548x; 1.0548x over previous
//
#include <hip/hip_runtime.h>

// ---------------------------------------------------------------------------
// TransformerBlock: out = LN( FFN(X) + X ),  X = LN( Q + softmax(QK^T/s) V )
// B=32, SQ=SK=D=1024.  bf16 MFMA GEMMs (fp32 accum, 256^2 8-phase schedule),
// LDS-vectorized bf16 epilogues with fused bias/residual, wave-per-row
// (barrier-free) softmax/LN.
// ---------------------------------------------------------------------------

typedef __attribute__((ext_vector_type(8))) short bf16x8;
typedef __attribute__((ext_vector_type(8))) unsigned short u16x8;
typedef __attribute__((ext_vector_type(4))) float f32x4;

__device__ __forceinline__ unsigned short f2bf(float f) {
  union { float f; unsigned u; } x; x.f = f;
  unsigned r = x.u + 0x7fffu + ((x.u >> 16) & 1u);  // round-to-nearest-even
  return (unsigned short)(r >> 16);
}
__device__ __forceinline__ float bf2f(unsigned short u) {
  union { unsigned u; float f; } x; x.u = (unsigned)u << 16;
  return x.f;
}

// ---------------- fused cast f32 -> bf16 for Q, K, W1, W2 -------------------
// (pinned at ~115us across 4 structural variants; kept as benched)
__global__ __launch_bounds__(256) void cast_all_kernel(
    const float* __restrict__ Q, const float* __restrict__ K,
    const float* __restrict__ W1, const float* __restrict__ W2,
    unsigned short* __restrict__ Qb, unsigned short* __restrict__ Kb,
    unsigned short* __restrict__ W1b, unsigned short* __restrict__ W2b) {
  const float* src; unsigned short* dst; long base;
  const int b = blockIdx.x;
  if (b < 1024)      { src = Q;  dst = Qb;  base = (long)b * 32768; }
  else if (b < 2048) { src = K;  dst = Kb;  base = (long)(b - 1024) * 32768; }
  else if (b < 2080) { src = W1; dst = W1b; base = (long)(b - 2048) * 32768; }
  else               { src = W2; dst = W2b; base = (long)(b - 2080) * 32768; }
  const int t = threadIdx.x;
#pragma unroll
  for (int it = 0; it < 4; ++it) {
    const long e0 = base + it * 8192 + t * 8;
    const float* p0 = src + e0;
    const float* p1 = src + e0 + 2048;
    const float* p2 = src + e0 + 4096;
    const float* p3 = src + e0 + 6144;
    f32x4 a0, b0, a1, b1, a2, b2, a3, b3;
    asm volatile("global_load_dwordx4 %0, %1, off" : "=v"(a0) : "v"(p0) : "memory");
    asm volatile("global_load_dwordx4 %0, %1, off offset:16" : "=v"(b0) : "v"(p0) : "memory");
    asm volatile("global_load_dwordx4 %0, %1, off" : "=v"(a1) : "v"(p1) : "memory");
    asm volatile("global_load_dwordx4 %0, %1, off offset:16" : "=v"(b1) : "v"(p1) : "memory");
    asm volatile("global_load_dwordx4 %0, %1, off" : "=v"(a2) : "v"(p2) : "memory");
    asm volatile("global_load_dwordx4 %0, %1, off offset:16" : "=v"(b2) : "v"(p2) : "memory");
    asm volatile("global_load_dwordx4 %0, %1, off" : "=v"(a3) : "v"(p3) : "memory");
    asm volatile("global_load_dwordx4 %0, %1, off offset:16" : "=v"(b3) : "v"(p3) : "memory");
    asm volatile("s_waitcnt vmcnt(0)" ::: "memory");
    __builtin_amdgcn_sched_barrier(0);
    u16x8 o;
    o[0] = f2bf(a0[0]); o[1] = f2bf(a0[1]); o[2] = f2bf(a0[2]); o[3] = f2bf(a0[3]);
    o[4] = f2bf(b0[0]); o[5] = f2bf(b0[1]); o[6] = f2bf(b0[2]); o[7] = f2bf(b0[3]);
    *(u16x8*)(dst + e0) = o;
    o[0] = f2bf(a1[0]); o[1] = f2bf(a1[1]); o[2] = f2bf(a1[2]); o[3] = f2bf(a1[3]);
    o[4] = f2bf(b1[0]); o[5] = f2bf(b1[1]); o[6] = f2bf(b1[2]); o[7] = f2bf(b1[3]);
    *(u16x8*)(dst + e0 + 2048) = o;
    o[0] = f2bf(a2[0]); o[1] = f2bf(a2[1]); o[2] = f2bf(a2[2]); o[3] = f2bf(a2[3]);
    o[4] = f2bf(b2[0]); o[5] = f2bf(b2[1]); o[6] = f2bf(b2[2]); o[7] = f2bf(b2[3]);
    *(u16x8*)(dst + e0 + 4096) = o;
    o[0] = f2bf(a3[0]); o[1] = f2bf(a3[1]); o[2] = f2bf(a3[2]); o[3] = f2bf(a3[3]);
    o[4] = f2bf(b3[0]); o[5] = f2bf(b3[1]); o[6] = f2bf(b3[2]); o[7] = f2bf(b3[3]);
    *(u16x8*)(dst + e0 + 6144) = o;
  }
}

// -------- per-batch transpose + cast: Vt[b][d][k] = bf16(V[b][k][d]) --------
__global__ __launch_bounds__(256) void transpose_cast_kernel(const float* __restrict__ V,
                                                             unsigned short* __restrict__ Vt) {
  __shared__ float tile[64][65];
  const int b = blockIdx.z;
  const float* Vb = V + (size_t)b * 1024 * 1024;
  unsigned short* Vtb = Vt + (size_t)b * 1024 * 1024;
  const int d0 = blockIdx.x * 64, k0 = blockIdx.y * 64;
  const int tc = (threadIdx.x & 15) * 4;
  const int tr = threadIdx.x >> 4;
  float4 v0 = *(const float4*)&Vb[(size_t)(k0 + tr) * 1024 + d0 + tc];
  float4 v1 = *(const float4*)&Vb[(size_t)(k0 + tr + 16) * 1024 + d0 + tc];
  float4 v2 = *(const float4*)&Vb[(size_t)(k0 + tr + 32) * 1024 + d0 + tc];
  float4 v3 = *(const float4*)&Vb[(size_t)(k0 + tr + 48) * 1024 + d0 + tc];
  __builtin_amdgcn_sched_barrier(0);
  tile[tr][tc] = v0.x; tile[tr][tc + 1] = v0.y; tile[tr][tc + 2] = v0.z; tile[tr][tc + 3] = v0.w;
  tile[tr + 16][tc] = v1.x; tile[tr + 16][tc + 1] = v1.y; tile[tr + 16][tc + 2] = v1.z; tile[tr + 16][tc + 3] = v1.w;
  tile[tr + 32][tc] = v2.x; tile[tr + 32][tc + 1] = v2.y; tile[tr + 32][tc + 2] = v2.z; tile[tr + 32][tc + 3] = v2.w;
  tile[tr + 48][tc] = v3.x; tile[tr + 48][tc + 1] = v3.y; tile[tr + 48][tc + 2] = v3.z; tile[tr + 48][tc + 3] = v3.w;
  __syncthreads();
  const int dr = threadIdx.x >> 2;
  const int k4 = (threadIdx.x & 3) * 16;
  u16x8 o0, o1;
#pragma unroll
  for (int j = 0; j < 8; ++j) o0[j] = f2bf(tile[k4 + j][dr]);
#pragma unroll
  for (int j = 0; j < 8; ++j) o1[j] = f2bf(tile[k4 + 8 + j][dr]);
  unsigned short* outp = &Vtb[(size_t)(d0 + dr) * 1024 + k0 + k4];
  *(u16x8*)outp = o0;
  *(u16x8*)(outp + 8) = o1;
}

// ---------------------------------------------------------------------------
// GEMM: C_bf16 = epi(A @ B^T)  (A:[M][K], B:[N][K] row-major bf16)
// 256x256 tile, BK=64, 8 waves (2Mx4N), 8-phase schedule, counted vmcnt(4),
// T2 XOR-swizzle both-sides, T5 setprio, T1 XCD swizzle, LDS-staged epilogue
// with 16B stores (half-wave per 512B row segment).
// EPI: 4 = acc*scale ; 6 = acc+resb ; 2 = relu(acc+bias) ; 7 = acc+bias+resb
// ---------------------------------------------------------------------------
template <int EPI>
__global__ __launch_bounds__(512, 2) void gemm8(
    const unsigned short* __restrict__ A, const unsigned short* __restrict__ B,
    const float* __restrict__ bias, const unsigned short* __restrict__ resb,
    unsigned short* __restrict__ Cout,
    int N, int K, long sA, long sB, long sC, float scale, int gx, int gxy) {

  __shared__ char smem[131072];

  const int nwg = gridDim.x;
  const int orig = blockIdx.x;
  const int wg = (orig & 7) * (nwg >> 3) + (orig >> 3);
  const int bz = wg / gxy;
  const int rem = wg - bz * gxy;
  const int by = rem / gx;
  const int bx = rem - by * gx;

  A += (size_t)bz * sA;
  B += (size_t)bz * sB;
  const size_t cbase = (size_t)bz * sC;
  const int brow = by * 256, bcol = bx * 256;

  const int tid = threadIdx.x;
  const int wave = tid >> 6, lane = tid & 63;
  const int wm = wave >> 2, wn = wave & 3;
  const int lr = lane & 15, kh = lane >> 4;
  const int swz = (lane & 7) << 4;

  const int s_r = wave * 8 + (lane >> 3);
  const int s_c = ((lane & 7) ^ (lane >> 3)) * 8;

  auto stg = [&](const unsigned short* g, int rowbase, int kt, int h, int mat) {
    char* region = smem + mat * 65536 + (kt & 1) * 32768;
#pragma unroll
    for (int j = 0; j < 2; ++j) {
      const unsigned short* src =
          g + (size_t)(rowbase + h * 128 + j * 64 + s_r) * K + kt * 64 + s_c;
      char* dst = region + h * 16384 + j * 8192 + wave * 1024;
      __builtin_amdgcn_global_load_lds(
          (const __attribute__((address_space(1))) void*)src,
          (__attribute__((address_space(3))) void*)dst, 16, 0, 0);
    }
  };

  auto rdA = [&](int c, int m, int k) -> bf16x8 {
    const int r = wm * 128 + m * 16 + lr;
    const int off = r * 128 + ((k * 64 + kh * 16) ^ swz);
    return *(const bf16x8*)(smem + c * 32768 + off);
  };
  auto rdB = [&](int c, int n, int k) -> bf16x8 {
    const int r = wn * 64 + n * 16 + lr;
    const int off = r * 128 + ((k * 64 + kh * 16) ^ swz);
    return *(const bf16x8*)(smem + 65536 + c * 32768 + off);
  };

  f32x4 acc[8][4];
#pragma unroll
  for (int m = 0; m < 8; ++m)
#pragma unroll
    for (int n = 0; n < 4; ++n)
#pragma unroll
      for (int i = 0; i < 4; ++i) acc[m][n][i] = 0.f;

  const int nkt = K >> 6;
  const int nI = nkt >> 1;

  stg(A, brow, 0, 0, 0); stg(A, brow, 0, 1, 0);
  stg(B, bcol, 0, 0, 1); stg(B, bcol, 0, 1, 1);
  stg(B, bcol, 1, 0, 1); stg(B, bcol, 1, 1, 1);
  stg(A, brow, 1, 0, 0); stg(A, brow, 1, 1, 0);
  asm volatile("s_waitcnt vmcnt(8)" ::: "memory");
  asm volatile("s_barrier" ::: "memory");

  bf16x8 bfrag[4][2];

  for (int I = 0; I < nI; ++I) {
    const bool nl = (I + 1 < nI);
#pragma unroll
    for (int g = 0; g < 2; ++g) {
#pragma unroll
      for (int q = 0; q < 4; ++q) {
        const int p = g * 4 + q;

        if (q == 0) {
#pragma unroll
          for (int n = 0; n < 4; ++n)
#pragma unroll
            for (int k = 0; k < 2; ++k) bfrag[n][k] = rdB(g, n, k);
        }
        bf16x8 afr[2][2];
#pragma unroll
        for (int mm = 0; mm < 2; ++mm)
#pragma unroll
          for (int k = 0; k < 2; ++k) afr[mm][k] = rdA(g, q * 2 + mm, k);

        if (p == 0) { if (I > 0) stg(A, brow, 2 * I + 1, 0, 0); }
        if (p == 1) { if (I > 0) stg(A, brow, 2 * I + 1, 1, 0);
                      if (nl) stg(B, bcol, 2 * I + 2, 0, 1); }
        if (p == 2) { if (nl) stg(B, bcol, 2 * I + 2, 1, 1); }
        if (p == 4) { if (nl) stg(A, brow, 2 * I + 2, 0, 0); }
        if (p == 5) { if (nl) { stg(A, brow, 2 * I + 2, 1, 0);
                                stg(B, bcol, 2 * I + 3, 0, 1); } }
        if (p == 6) { if (nl) stg(B, bcol, 2 * I + 3, 1, 1); }

        asm volatile("s_barrier" ::: "memory");  // barrier1 (no vmem drain)

        __builtin_amdgcn_s_setprio(1);
#pragma unroll
        for (int k = 0; k < 2; ++k)
#pragma unroll
          for (int mm = 0; mm < 2; ++mm)
#pragma unroll
            for (int n = 0; n < 4; ++n)
              acc[q * 2 + mm][n] = __builtin_amdgcn_mfma_f32_16x16x32_bf16(
                  afr[mm][k], bfrag[n][k], acc[q * 2 + mm][n], 0, 0, 0);
        __builtin_amdgcn_s_setprio(0);

        if (q == 3) {
          if (g == 0 && !nl) asm volatile("s_waitcnt vmcnt(0)" ::: "memory");
          else               asm volatile("s_waitcnt vmcnt(4)" ::: "memory");
        }
        asm volatile("s_barrier" ::: "memory");  // barrier2
      }
    }
  }

  // ---- LDS-staged epilogue: 16B stores, half-wave per 512B row segment ----
  float* eplds = (float*)smem;
#pragma unroll
  for (int pass = 0; pass < 2; ++pass) {
    __syncthreads();
    if (wm == pass) {
#pragma unroll
      for (int m = 0; m < 8; ++m)
#pragma unroll
        for (int n = 0; n < 4; ++n)
#pragma unroll
          for (int i = 0; i < 4; ++i) {
            const int r = m * 16 + kh * 4 + i;
            const int c = wn * 64 + n * 16 + lr;
            eplds[r * 256 + (c ^ ((r & 7) << 2))] = acc[m][n][i];
          }
    }
    __syncthreads();
#pragma unroll
    for (int j = 0; j < 8; ++j) {
      const int rl = j * 16 + wave * 2 + (lane >> 5);
      const int grow = brow + pass * 128 + rl;
      const int cl = (lane & 31) * 8;
      const size_t idx = cbase + (size_t)grow * N + bcol + cl;
      const int e0 = cl ^ ((rl & 7) << 2);
      float4 va = *(const float4*)&eplds[rl * 256 + e0];
      float4 vb = *(const float4*)&eplds[rl * 256 + (e0 ^ 4)];
      float o[8] = {va.x, va.y, va.z, va.w, vb.x, vb.y, vb.z, vb.w};
      if (EPI == 4) {
#pragma unroll
        for (int k = 0; k < 8; ++k) o[k] *= scale;
      } else if (EPI == 6) {
        u16x8 r = *(const u16x8*)&resb[idx];
#pragma unroll
        for (int k = 0; k < 8; ++k) o[k] += bf2f(r[k]);
      } else if (EPI == 2) {
        float4 b0 = *(const float4*)&bias[bcol + cl];
        float4 b1 = *(const float4*)&bias[bcol + cl + 4];
        float bb[8] = {b0.x, b0.y, b0.z, b0.w, b1.x, b1.y, b1.z, b1.w};
#pragma unroll
        for (int k = 0; k < 8; ++k) o[k] = fmaxf(o[k] + bb[k], 0.f);
      } else {  // EPI == 7
        float4 b0 = *(const float4*)&bias[bcol + cl];
        float4 b1 = *(const float4*)&bias[bcol + cl + 4];
        float bb[8] = {b0.x, b0.y, b0.z, b0.w, b1.x, b1.y, b1.z, b1.w};
        u16x8 r = *(const u16x8*)&resb[idx];
#pragma unroll
        for (int k = 0; k < 8; ++k) o[k] += bb[k] + bf2f(r[k]);
      }
      u16x8 ov;
#pragma unroll
      for (int k = 0; k < 8; ++k) ov[k] = f2bf(o[k]);
      *(u16x8*)&Cout[idx] = ov;
    }
  }
}

// ------- wave-per-row softmax (in-place bf16), barrier-free, grid 4096 ------
__global__ __launch_bounds__(512) void softmax_kernel(unsigned short* __restrict__ S) {
  const size_t row = (size_t)blockIdx.x * 8 + (threadIdx.x >> 6);
  const int lane = threadIdx.x & 63;
  unsigned short* p0 = S + row * 1024 + lane * 8;
  u16x8 u0 = *(const u16x8*)p0;
  u16x8 u1 = *(const u16x8*)(p0 + 512);
  float v[16];
#pragma unroll
  for (int j = 0; j < 8; ++j) { v[j] = bf2f(u0[j]); v[8 + j] = bf2f(u1[j]); }
  float mx = v[0];
#pragma unroll
  for (int j = 1; j < 16; ++j) mx = fmaxf(mx, v[j]);
#pragma unroll
  for (int o = 32; o; o >>= 1) mx = fmaxf(mx, __shfl_xor(mx, o));
  float s = 0.f;
#pragma unroll
  for (int j = 0; j < 16; ++j) { v[j] = __expf(v[j] - mx); s += v[j]; }
#pragma unroll
  for (int o = 32; o; o >>= 1) s += __shfl_xor(s, o);
  const float inv = 1.f / s;
#pragma unroll
  for (int j = 0; j < 8; ++j) { u0[j] = f2bf(v[j] * inv); u1[j] = f2bf(v[8 + j] * inv); }
  *(u16x8*)p0 = u0;
  *(u16x8*)(p0 + 512) = u1;
}

// ------ wave-per-row LayerNorm (bf16 in), barrier-free, grid 4096 -----------
// writes fp32 (Xf) and/or bf16 (Xb).
__global__ __launch_bounds__(512) void ln_bf_kernel(
    const unsigned short* __restrict__ A,
    const float* __restrict__ gamma, const float* __restrict__ beta,
    float* __restrict__ Xf, unsigned short* __restrict__ Xb) {
  const size_t row = (size_t)blockIdx.x * 8 + (threadIdx.x >> 6);
  const int lane = threadIdx.x & 63;
  const int c0 = lane * 8;
  const unsigned short* p0 = A + row * 1024 + c0;
  u16x8 u0 = *(const u16x8*)p0;
  u16x8 u1 = *(const u16x8*)(p0 + 512);
  float x[16];
#pragma unroll
  for (int j = 0; j < 8; ++j) { x[j] = bf2f(u0[j]); x[8 + j] = bf2f(u1[j]); }
  float s = 0.f, q = 0.f;
#pragma unroll
  for (int j = 0; j < 16; ++j) { s += x[j]; q += x[j] * x[j]; }
#pragma unroll
  for (int o = 32; o; o >>= 1) { s += __shfl_xor(s, o); q += __shfl_xor(q, o); }
  const float mu = s * (1.f / 1024.f);
  const float var = q * (1.f / 1024.f) - mu * mu;
  const float rs = rsqrtf(var + 1e-5f);
  float4 g0 = *(const float4*)(gamma + c0);
  float4 g1 = *(const float4*)(gamma + c0 + 4);
  float4 g2 = *(const float4*)(gamma + 512 + c0);
  float4 g3 = *(const float4*)(gamma + 512 + c0 + 4);
  float4 b0 = *(const float4*)(beta + c0);
  float4 b1 = *(const float4*)(beta + c0 + 4);
  float4 b2 = *(const float4*)(beta + 512 + c0);
  float4 b3 = *(const float4*)(beta + 512 + c0 + 4);
  float gg[16] = {g0.x, g0.y, g0.z, g0.w, g1.x, g1.y, g1.z, g1.w,
                  g2.x, g2.y, g2.z, g2.w, g3.x, g3.y, g3.z, g3.w};
  float bb[16] = {b0.x, b0.y, b0.z, b0.w, b1.x, b1.y, b1.z, b1.w,
                  b2.x, b2.y, b2.z, b2.w, b3.x, b3.y, b3.z, b3.w};
  float o[16];
#pragma unroll
  for (int j = 0; j < 16; ++j) o[j] = (x[j] - mu) * rs * gg[j] + bb[j];
  if (Xf) {
    float* w = Xf + row * 1024 + c0;
    float4 f;
    f.x = o[0];  f.y = o[1];  f.z = o[2];  f.w = o[3];  *(float4*)w = f;
    f.x = o[4];  f.y = o[5];  f.z = o[6];  f.w = o[7];  *(float4*)(w + 4) = f;
    f.x = o[8];  f.y = o[9];  f.z = o[10]; f.w = o[11]; *(float4*)(w + 512) = f;
    f.x = o[12]; f.y = o[13]; f.z = o[14]; f.w = o[15]; *(float4*)(w + 516) = f;
  }
  if (Xb) {
    u16x8 w0, w1;
#pragma unroll
    for (int j = 0; j < 8; ++j) { w0[j] = f2bf(o[j]); w1[j] = f2bf(o[8 + j]); }
    unsigned short* w = Xb + row * 1024 + c0;
    *(u16x8*)w = w0;
    *(u16x8*)(w + 512) = w1;
  }
}

// ---------------------------------------------------------------------------
extern "C" void kernel_launch(void* const* d_in, const int* in_sizes, int n_in,
                              void* d_out, int out_size, void* d_ws, size_t ws_size,
                              hipStream_t stream) {
  const float* Q    = (const float*)d_in[0];
  const float* Km   = (const float*)d_in[1];
  const float* V    = (const float*)d_in[2];
  const float* W1   = (const float*)d_in[3];
  const float* b1   = (const float*)d_in[4];
  const float* W2   = (const float*)d_in[5];
  const float* b2   = (const float*)d_in[6];
  const float* gamma = (const float*)d_in[7];
  const float* beta  = (const float*)d_in[8];
  float* out = (float*)d_out;

  char* ws = (char*)d_ws;
  const size_t NEL = (size_t)32 * 1024 * 1024;
  unsigned short* Qb  = (unsigned short*)ws;
  unsigned short* Kb  = Qb + NEL;
  unsigned short* Vtb = Kb + NEL;
  unsigned short* Sb  = Vtb + NEL;
  unsigned short* VAb = Sb + NEL;
  unsigned short* Xb  = VAb + NEL;
  unsigned short* W1b = Xb + NEL;
  unsigned short* W2b = W1b + 1024 * 1024;
  unsigned short* Hb  = Sb;    // alias: P dead after GEMM2
  unsigned short* Fb  = VAb;   // alias: VAb dead after ln1

  const long M1 = 1024L * 1024L;
  const float scale = 1.0f / (sqrtf(1024.0f) + 1e-8f);

  cast_all_kernel<<<2112, 256, 0, stream>>>(Q, Km, W1, W2, Qb, Kb, W1b, W2b);
  transpose_cast_kernel<<<dim3(16, 16, 32), 256, 0, stream>>>(V, Vtb);

  // Sb = bf16((Q K^T) * scale)    [grid 4x4x32 = 512]
  gemm8<4><<<512, 512, 0, stream>>>(Qb, Kb, nullptr, nullptr, Sb,
                                    1024, 1024, M1, M1, M1, scale, 4, 16);
  softmax_kernel<<<4096, 512, 0, stream>>>(Sb);
  // VAb = bf16(P @ Vt^T + Qb)     (residual fused, bf16)
  gemm8<6><<<512, 512, 0, stream>>>(Sb, Vtb, nullptr, Qb, VAb,
                                    1024, 1024, M1, M1, M1, 1.0f, 4, 16);
  // Xb = bf16(LN(VAb))
  ln_bf_kernel<<<4096, 512, 0, stream>>>(VAb, gamma, beta, nullptr, Xb);
  // Hb = bf16(relu(Xb @ W1^T + b1))   [M=32768: grid 4x128]
  gemm8<2><<<512, 512, 0, stream>>>(Xb, W1b, b1, nullptr, Hb,
                                    1024, 1024, 0, 0, 0, 1.0f, 4, 512);
  // Fb = bf16(Hb @ W2^T + b2 + Xb)    (residual fused)
  gemm8<7><<<512, 512, 0, stream>>>(Hb, W2b, b2, Xb, Fb,
                                    1024, 1024, 0, 0, 0, 1.0f, 4, 512);
  // out = LN(Fb)  (fp32 final)
  ln_bf_kernel<<<4096, 512, 0, stream>>>(Fb, gamma, beta, out, nullptr);
}

// Round 15
// 504.537 us; speedup vs baseline: 1.0811x; 1.0250x over previous
//
#include <hip/hip_runtime.h>

// ---------------------------------------------------------------------------
// TransformerBlock: out = LN( FFN(X) + X ),  X = LN( Q + softmax(QK^T/s) V )
// B=32, SQ=SK=D=1024.  bf16 MFMA GEMMs (fp32 accum, 256^2 8-phase schedule,
// single-barrier phases), LDS-vectorized bf16 epilogues with fused
// bias/residual, wave-per-row (barrier-free) softmax/LN.
// ---------------------------------------------------------------------------

typedef __attribute__((ext_vector_type(8))) short bf16x8;
typedef __attribute__((ext_vector_type(8))) unsigned short u16x8;
typedef __attribute__((ext_vector_type(4))) float f32x4;

__device__ __forceinline__ unsigned short f2bf(float f) {
  union { float f; unsigned u; } x; x.f = f;
  unsigned r = x.u + 0x7fffu + ((x.u >> 16) & 1u);  // round-to-nearest-even
  return (unsigned short)(r >> 16);
}
__device__ __forceinline__ float bf2f(unsigned short u) {
  union { unsigned u; float f; } x; x.u = (unsigned)u << 16;
  return x.f;
}

// ---------------- fused cast f32 -> bf16 for Q, K, W1, W2 -------------------
// (pinned at ~115us across 4 structural variants; kept as benched)
__global__ __launch_bounds__(256) void cast_all_kernel(
    const float* __restrict__ Q, const float* __restrict__ K,
    const float* __restrict__ W1, const float* __restrict__ W2,
    unsigned short* __restrict__ Qb, unsigned short* __restrict__ Kb,
    unsigned short* __restrict__ W1b, unsigned short* __restrict__ W2b) {
  const float* src; unsigned short* dst; long base;
  const int b = blockIdx.x;
  if (b < 1024)      { src = Q;  dst = Qb;  base = (long)b * 32768; }
  else if (b < 2048) { src = K;  dst = Kb;  base = (long)(b - 1024) * 32768; }
  else if (b < 2080) { src = W1; dst = W1b; base = (long)(b - 2048) * 32768; }
  else               { src = W2; dst = W2b; base = (long)(b - 2080) * 32768; }
  const int t = threadIdx.x;
#pragma unroll
  for (int it = 0; it < 4; ++it) {
    const long e0 = base + it * 8192 + t * 8;
    const float* p0 = src + e0;
    const float* p1 = src + e0 + 2048;
    const float* p2 = src + e0 + 4096;
    const float* p3 = src + e0 + 6144;
    f32x4 a0, b0, a1, b1, a2, b2, a3, b3;
    asm volatile("global_load_dwordx4 %0, %1, off" : "=v"(a0) : "v"(p0) : "memory");
    asm volatile("global_load_dwordx4 %0, %1, off offset:16" : "=v"(b0) : "v"(p0) : "memory");
    asm volatile("global_load_dwordx4 %0, %1, off" : "=v"(a1) : "v"(p1) : "memory");
    asm volatile("global_load_dwordx4 %0, %1, off offset:16" : "=v"(b1) : "v"(p1) : "memory");
    asm volatile("global_load_dwordx4 %0, %1, off" : "=v"(a2) : "v"(p2) : "memory");
    asm volatile("global_load_dwordx4 %0, %1, off offset:16" : "=v"(b2) : "v"(p2) : "memory");
    asm volatile("global_load_dwordx4 %0, %1, off" : "=v"(a3) : "v"(p3) : "memory");
    asm volatile("global_load_dwordx4 %0, %1, off offset:16" : "=v"(b3) : "v"(p3) : "memory");
    asm volatile("s_waitcnt vmcnt(0)" ::: "memory");
    __builtin_amdgcn_sched_barrier(0);
    u16x8 o;
    o[0] = f2bf(a0[0]); o[1] = f2bf(a0[1]); o[2] = f2bf(a0[2]); o[3] = f2bf(a0[3]);
    o[4] = f2bf(b0[0]); o[5] = f2bf(b0[1]); o[6] = f2bf(b0[2]); o[7] = f2bf(b0[3]);
    *(u16x8*)(dst + e0) = o;
    o[0] = f2bf(a1[0]); o[1] = f2bf(a1[1]); o[2] = f2bf(a1[2]); o[3] = f2bf(a1[3]);
    o[4] = f2bf(b1[0]); o[5] = f2bf(b1[1]); o[6] = f2bf(b1[2]); o[7] = f2bf(b1[3]);
    *(u16x8*)(dst + e0 + 2048) = o;
    o[0] = f2bf(a2[0]); o[1] = f2bf(a2[1]); o[2] = f2bf(a2[2]); o[3] = f2bf(a2[3]);
    o[4] = f2bf(b2[0]); o[5] = f2bf(b2[1]); o[6] = f2bf(b2[2]); o[7] = f2bf(b2[3]);
    *(u16x8*)(dst + e0 + 4096) = o;
    o[0] = f2bf(a3[0]); o[1] = f2bf(a3[1]); o[2] = f2bf(a3[2]); o[3] = f2bf(a3[3]);
    o[4] = f2bf(b3[0]); o[5] = f2bf(b3[1]); o[6] = f2bf(b3[2]); o[7] = f2bf(b3[3]);
    *(u16x8*)(dst + e0 + 6144) = o;
  }
}

// -------- per-batch transpose + cast: Vt[b][d][k] = bf16(V[b][k][d]) --------
__global__ __launch_bounds__(256) void transpose_cast_kernel(const float* __restrict__ V,
                                                             unsigned short* __restrict__ Vt) {
  __shared__ float tile[64][65];
  const int b = blockIdx.z;
  const float* Vb = V + (size_t)b * 1024 * 1024;
  unsigned short* Vtb = Vt + (size_t)b * 1024 * 1024;
  const int d0 = blockIdx.x * 64, k0 = blockIdx.y * 64;
  const int tc = (threadIdx.x & 15) * 4;
  const int tr = threadIdx.x >> 4;
  float4 v0 = *(const float4*)&Vb[(size_t)(k0 + tr) * 1024 + d0 + tc];
  float4 v1 = *(const float4*)&Vb[(size_t)(k0 + tr + 16) * 1024 + d0 + tc];
  float4 v2 = *(const float4*)&Vb[(size_t)(k0 + tr + 32) * 1024 + d0 + tc];
  float4 v3 = *(const float4*)&Vb[(size_t)(k0 + tr + 48) * 1024 + d0 + tc];
  __builtin_amdgcn_sched_barrier(0);
  tile[tr][tc] = v0.x; tile[tr][tc + 1] = v0.y; tile[tr][tc + 2] = v0.z; tile[tr][tc + 3] = v0.w;
  tile[tr + 16][tc] = v1.x; tile[tr + 16][tc + 1] = v1.y; tile[tr + 16][tc + 2] = v1.z; tile[tr + 16][tc + 3] = v1.w;
  tile[tr + 32][tc] = v2.x; tile[tr + 32][tc + 1] = v2.y; tile[tr + 32][tc + 2] = v2.z; tile[tr + 32][tc + 3] = v2.w;
  tile[tr + 48][tc] = v3.x; tile[tr + 48][tc + 1] = v3.y; tile[tr + 48][tc + 2] = v3.z; tile[tr + 48][tc + 3] = v3.w;
  __syncthreads();
  const int dr = threadIdx.x >> 2;
  const int k4 = (threadIdx.x & 3) * 16;
  u16x8 o0, o1;
#pragma unroll
  for (int j = 0; j < 8; ++j) o0[j] = f2bf(tile[k4 + j][dr]);
#pragma unroll
  for (int j = 0; j < 8; ++j) o1[j] = f2bf(tile[k4 + 8 + j][dr]);
  unsigned short* outp = &Vtb[(size_t)(d0 + dr) * 1024 + k0 + k4];
  *(u16x8*)outp = o0;
  *(u16x8*)(outp + 8) = o1;
}

// ---------------------------------------------------------------------------
// GEMM: C_bf16 = epi(A @ B^T)  (A:[M][K], B:[N][K] row-major bf16)
// 256x256 tile, BK=64, 8 waves (2Mx4N), 8-phase schedule with SINGLE barrier
// per phase (barrier2 alone fences all stage-vs-read hazards; skew bounded to
// one phase), counted vmcnt(4), T2 XOR-swizzle both-sides, T5 setprio,
// T1 XCD swizzle, LDS-staged epilogue with 16B stores.
// EPI: 4 = acc*scale ; 6 = acc+resb ; 2 = relu(acc+bias) ; 7 = acc+bias+resb
// ---------------------------------------------------------------------------
template <int EPI>
__global__ __launch_bounds__(512, 2) void gemm8(
    const unsigned short* __restrict__ A, const unsigned short* __restrict__ B,
    const float* __restrict__ bias, const unsigned short* __restrict__ resb,
    unsigned short* __restrict__ Cout,
    int N, int K, long sA, long sB, long sC, float scale, int gx, int gxy) {

  __shared__ char smem[131072];

  const int nwg = gridDim.x;
  const int orig = blockIdx.x;
  const int wg = (orig & 7) * (nwg >> 3) + (orig >> 3);
  const int bz = wg / gxy;
  const int rem = wg - bz * gxy;
  const int by = rem / gx;
  const int bx = rem - by * gx;

  A += (size_t)bz * sA;
  B += (size_t)bz * sB;
  const size_t cbase = (size_t)bz * sC;
  const int brow = by * 256, bcol = bx * 256;

  const int tid = threadIdx.x;
  const int wave = tid >> 6, lane = tid & 63;
  const int wm = wave >> 2, wn = wave & 3;
  const int lr = lane & 15, kh = lane >> 4;
  const int swz = (lane & 7) << 4;

  const int s_r = wave * 8 + (lane >> 3);
  const int s_c = ((lane & 7) ^ (lane >> 3)) * 8;

  auto stg = [&](const unsigned short* g, int rowbase, int kt, int h, int mat) {
    char* region = smem + mat * 65536 + (kt & 1) * 32768;
#pragma unroll
    for (int j = 0; j < 2; ++j) {
      const unsigned short* src =
          g + (size_t)(rowbase + h * 128 + j * 64 + s_r) * K + kt * 64 + s_c;
      char* dst = region + h * 16384 + j * 8192 + wave * 1024;
      __builtin_amdgcn_global_load_lds(
          (const __attribute__((address_space(1))) void*)src,
          (__attribute__((address_space(3))) void*)dst, 16, 0, 0);
    }
  };

  auto rdA = [&](int c, int m, int k) -> bf16x8 {
    const int r = wm * 128 + m * 16 + lr;
    const int off = r * 128 + ((k * 64 + kh * 16) ^ swz);
    return *(const bf16x8*)(smem + c * 32768 + off);
  };
  auto rdB = [&](int c, int n, int k) -> bf16x8 {
    const int r = wn * 64 + n * 16 + lr;
    const int off = r * 128 + ((k * 64 + kh * 16) ^ swz);
    return *(const bf16x8*)(smem + 65536 + c * 32768 + off);
  };

  f32x4 acc[8][4];
#pragma unroll
  for (int m = 0; m < 8; ++m)
#pragma unroll
    for (int n = 0; n < 4; ++n)
#pragma unroll
      for (int i = 0; i < 4; ++i) acc[m][n][i] = 0.f;

  const int nkt = K >> 6;
  const int nI = nkt >> 1;

  stg(A, brow, 0, 0, 0); stg(A, brow, 0, 1, 0);
  stg(B, bcol, 0, 0, 1); stg(B, bcol, 0, 1, 1);
  stg(B, bcol, 1, 0, 1); stg(B, bcol, 1, 1, 1);
  stg(A, brow, 1, 0, 0); stg(A, brow, 1, 1, 0);
  asm volatile("s_waitcnt vmcnt(8)" ::: "memory");
  asm volatile("s_barrier" ::: "memory");

  bf16x8 bfrag[4][2];

  for (int I = 0; I < nI; ++I) {
    const bool nl = (I + 1 < nI);
#pragma unroll
    for (int g = 0; g < 2; ++g) {
#pragma unroll
      for (int q = 0; q < 4; ++q) {
        const int p = g * 4 + q;

        if (q == 0) {
#pragma unroll
          for (int n = 0; n < 4; ++n)
#pragma unroll
            for (int k = 0; k < 2; ++k) bfrag[n][k] = rdB(g, n, k);
        }
        bf16x8 afr[2][2];
#pragma unroll
        for (int mm = 0; mm < 2; ++mm)
#pragma unroll
          for (int k = 0; k < 2; ++k) afr[mm][k] = rdA(g, q * 2 + mm, k);

        if (p == 0) { if (I > 0) stg(A, brow, 2 * I + 1, 0, 0); }
        if (p == 1) { if (I > 0) stg(A, brow, 2 * I + 1, 1, 0);
                      if (nl) stg(B, bcol, 2 * I + 2, 0, 1); }
        if (p == 2) { if (nl) stg(B, bcol, 2 * I + 2, 1, 1); }
        if (p == 4) { if (nl) stg(A, brow, 2 * I + 2, 0, 0); }
        if (p == 5) { if (nl) { stg(A, brow, 2 * I + 2, 1, 0);
                                stg(B, bcol, 2 * I + 3, 0, 1); } }
        if (p == 6) { if (nl) stg(B, bcol, 2 * I + 3, 1, 1); }

        // (barrier1 removed: barrier2 alone fences stage-vs-read — every
        //  staged region's last reads retire >=1 barrier2 earlier; wave skew
        //  is bounded to one phase by barrier2.)

        __builtin_amdgcn_s_setprio(1);
#pragma unroll
        for (int k = 0; k < 2; ++k)
#pragma unroll
          for (int mm = 0; mm < 2; ++mm)
#pragma unroll
            for (int n = 0; n < 4; ++n)
              acc[q * 2 + mm][n] = __builtin_amdgcn_mfma_f32_16x16x32_bf16(
                  afr[mm][k], bfrag[n][k], acc[q * 2 + mm][n], 0, 0, 0);
        __builtin_amdgcn_s_setprio(0);

        if (q == 3) {
          if (g == 0 && !nl) asm volatile("s_waitcnt vmcnt(0)" ::: "memory");
          else               asm volatile("s_waitcnt vmcnt(4)" ::: "memory");
        }
        asm volatile("s_barrier" ::: "memory");  // barrier2 (the load-visibility + read-retire fence)
      }
    }
  }

  // ---- LDS-staged epilogue: 16B stores, half-wave per 512B row segment ----
  float* eplds = (float*)smem;
#pragma unroll
  for (int pass = 0; pass < 2; ++pass) {
    __syncthreads();
    if (wm == pass) {
#pragma unroll
      for (int m = 0; m < 8; ++m)
#pragma unroll
        for (int n = 0; n < 4; ++n)
#pragma unroll
          for (int i = 0; i < 4; ++i) {
            const int r = m * 16 + kh * 4 + i;
            const int c = wn * 64 + n * 16 + lr;
            eplds[r * 256 + (c ^ ((r & 7) << 2))] = acc[m][n][i];
          }
    }
    __syncthreads();
#pragma unroll
    for (int j = 0; j < 8; ++j) {
      const int rl = j * 16 + wave * 2 + (lane >> 5);
      const int grow = brow + pass * 128 + rl;
      const int cl = (lane & 31) * 8;
      const size_t idx = cbase + (size_t)grow * N + bcol + cl;
      const int e0 = cl ^ ((rl & 7) << 2);
      float4 va = *(const float4*)&eplds[rl * 256 + e0];
      float4 vb = *(const float4*)&eplds[rl * 256 + (e0 ^ 4)];
      float o[8] = {va.x, va.y, va.z, va.w, vb.x, vb.y, vb.z, vb.w};
      if (EPI == 4) {
#pragma unroll
        for (int k = 0; k < 8; ++k) o[k] *= scale;
      } else if (EPI == 6) {
        u16x8 r = *(const u16x8*)&resb[idx];
#pragma unroll
        for (int k = 0; k < 8; ++k) o[k] += bf2f(r[k]);
      } else if (EPI == 2) {
        float4 b0 = *(const float4*)&bias[bcol + cl];
        float4 b1 = *(const float4*)&bias[bcol + cl + 4];
        float bb[8] = {b0.x, b0.y, b0.z, b0.w, b1.x, b1.y, b1.z, b1.w};
#pragma unroll
        for (int k = 0; k < 8; ++k) o[k] = fmaxf(o[k] + bb[k], 0.f);
      } else {  // EPI == 7
        float4 b0 = *(const float4*)&bias[bcol + cl];
        float4 b1 = *(const float4*)&bias[bcol + cl + 4];
        float bb[8] = {b0.x, b0.y, b0.z, b0.w, b1.x, b1.y, b1.z, b1.w};
        u16x8 r = *(const u16x8*)&resb[idx];
#pragma unroll
        for (int k = 0; k < 8; ++k) o[k] += bb[k] + bf2f(r[k]);
      }
      u16x8 ov;
#pragma unroll
      for (int k = 0; k < 8; ++k) ov[k] = f2bf(o[k]);
      *(u16x8*)&Cout[idx] = ov;
    }
  }
}

// ------- wave-per-row softmax (in-place bf16), barrier-free, grid 4096 ------
__global__ __launch_bounds__(512) void softmax_kernel(unsigned short* __restrict__ S) {
  const size_t row = (size_t)blockIdx.x * 8 + (threadIdx.x >> 6);
  const int lane = threadIdx.x & 63;
  unsigned short* p0 = S + row * 1024 + lane * 8;
  u16x8 u0 = *(const u16x8*)p0;
  u16x8 u1 = *(const u16x8*)(p0 + 512);
  float v[16];
#pragma unroll
  for (int j = 0; j < 8; ++j) { v[j] = bf2f(u0[j]); v[8 + j] = bf2f(u1[j]); }
  float mx = v[0];
#pragma unroll
  for (int j = 1; j < 16; ++j) mx = fmaxf(mx, v[j]);
#pragma unroll
  for (int o = 32; o; o >>= 1) mx = fmaxf(mx, __shfl_xor(mx, o));
  float s = 0.f;
#pragma unroll
  for (int j = 0; j < 16; ++j) { v[j] = __expf(v[j] - mx); s += v[j]; }
#pragma unroll
  for (int o = 32; o; o >>= 1) s += __shfl_xor(s, o);
  const float inv = 1.f / s;
#pragma unroll
  for (int j = 0; j < 8; ++j) { u0[j] = f2bf(v[j] * inv); u1[j] = f2bf(v[8 + j] * inv); }
  *(u16x8*)p0 = u0;
  *(u16x8*)(p0 + 512) = u1;
}

// ------ wave-per-row LayerNorm (bf16 in), barrier-free, grid 4096 -----------
__global__ __launch_bounds__(512) void ln_bf_kernel(
    const unsigned short* __restrict__ A,
    const float* __restrict__ gamma, const float* __restrict__ beta,
    float* __restrict__ Xf, unsigned short* __restrict__ Xb) {
  const size_t row = (size_t)blockIdx.x * 8 + (threadIdx.x >> 6);
  const int lane = threadIdx.x & 63;
  const int c0 = lane * 8;
  const unsigned short* p0 = A + row * 1024 + c0;
  u16x8 u0 = *(const u16x8*)p0;
  u16x8 u1 = *(const u16x8*)(p0 + 512);
  float x[16];
#pragma unroll
  for (int j = 0; j < 8; ++j) { x[j] = bf2f(u0[j]); x[8 + j] = bf2f(u1[j]); }
  float s = 0.f, q = 0.f;
#pragma unroll
  for (int j = 0; j < 16; ++j) { s += x[j]; q += x[j] * x[j]; }
#pragma unroll
  for (int o = 32; o; o >>= 1) { s += __shfl_xor(s, o); q += __shfl_xor(q, o); }
  const float mu = s * (1.f / 1024.f);
  const float var = q * (1.f / 1024.f) - mu * mu;
  const float rs = rsqrtf(var + 1e-5f);
  float4 g0 = *(const float4*)(gamma + c0);
  float4 g1 = *(const float4*)(gamma + c0 + 4);
  float4 g2 = *(const float4*)(gamma + 512 + c0);
  float4 g3 = *(const float4*)(gamma + 512 + c0 + 4);
  float4 b0 = *(const float4*)(beta + c0);
  float4 b1 = *(const float4*)(beta + c0 + 4);
  float4 b2 = *(const float4*)(beta + 512 + c0);
  float4 b3 = *(const float4*)(beta + 512 + c0 + 4);
  float gg[16] = {g0.x, g0.y, g0.z, g0.w, g1.x, g1.y, g1.z, g1.w,
                  g2.x, g2.y, g2.z, g2.w, g3.x, g3.y, g3.z, g3.w};
  float bb[16] = {b0.x, b0.y, b0.z, b0.w, b1.x, b1.y, b1.z, b1.w,
                  b2.x, b2.y, b2.z, b2.w, b3.x, b3.y, b3.z, b3.w};
  float o[16];
#pragma unroll
  for (int j = 0; j < 16; ++j) o[j] = (x[j] - mu) * rs * gg[j] + bb[j];
  if (Xf) {
    float* w = Xf + row * 1024 + c0;
    float4 f;
    f.x = o[0];  f.y = o[1];  f.z = o[2];  f.w = o[3];  *(float4*)w = f;
    f.x = o[4];  f.y = o[5];  f.z = o[6];  f.w = o[7];  *(float4*)(w + 4) = f;
    f.x = o[8];  f.y = o[9];  f.z = o[10]; f.w = o[11]; *(float4*)(w + 512) = f;
    f.x = o[12]; f.y = o[13]; f.z = o[14]; f.w = o[15]; *(float4*)(w + 516) = f;
  }
  if (Xb) {
    u16x8 w0, w1;
#pragma unroll
    for (int j = 0; j < 8; ++j) { w0[j] = f2bf(o[j]); w1[j] = f2bf(o[8 + j]); }
    unsigned short* w = Xb + row * 1024 + c0;
    *(u16x8*)w = w0;
    *(u16x8*)(w + 512) = w1;
  }
}

// ---------------------------------------------------------------------------
extern "C" void kernel_launch(void* const* d_in, const int* in_sizes, int n_in,
                              void* d_out, int out_size, void* d_ws, size_t ws_size,
                              hipStream_t stream) {
  const float* Q    = (const float*)d_in[0];
  const float* Km   = (const float*)d_in[1];
  const float* V    = (const float*)d_in[2];
  const float* W1   = (const float*)d_in[3];
  const float* b1   = (const float*)d_in[4];
  const float* W2   = (const float*)d_in[5];
  const float* b2   = (const float*)d_in[6];
  const float* gamma = (const float*)d_in[7];
  const float* beta  = (const float*)d_in[8];
  float* out = (float*)d_out;

  char* ws = (char*)d_ws;
  const size_t NEL = (size_t)32 * 1024 * 1024;
  unsigned short* Qb  = (unsigned short*)ws;
  unsigned short* Kb  = Qb + NEL;
  unsigned short* Vtb = Kb + NEL;
  unsigned short* Sb  = Vtb + NEL;
  unsigned short* VAb = Sb + NEL;
  unsigned short* Xb  = VAb + NEL;
  unsigned short* W1b = Xb + NEL;
  unsigned short* W2b = W1b + 1024 * 1024;
  unsigned short* Hb  = Sb;    // alias: P dead after GEMM2
  unsigned short* Fb  = VAb;   // alias: VAb dead after ln1

  const long M1 = 1024L * 1024L;
  const float scale = 1.0f / (sqrtf(1024.0f) + 1e-8f);

  cast_all_kernel<<<2112, 256, 0, stream>>>(Q, Km, W1, W2, Qb, Kb, W1b, W2b);
  transpose_cast_kernel<<<dim3(16, 16, 32), 256, 0, stream>>>(V, Vtb);

  // Sb = bf16((Q K^T) * scale)    [grid 4x4x32 = 512]
  gemm8<4><<<512, 512, 0, stream>>>(Qb, Kb, nullptr, nullptr, Sb,
                                    1024, 1024, M1, M1, M1, scale, 4, 16);
  softmax_kernel<<<4096, 512, 0, stream>>>(Sb);
  // VAb = bf16(P @ Vt^T + Qb)     (residual fused, bf16)
  gemm8<6><<<512, 512, 0, stream>>>(Sb, Vtb, nullptr, Qb, VAb,
                                    1024, 1024, M1, M1, M1, 1.0f, 4, 16);
  // Xb = bf16(LN(VAb))
  ln_bf_kernel<<<4096, 512, 0, stream>>>(VAb, gamma, beta, nullptr, Xb);
  // Hb = bf16(relu(Xb @ W1^T + b1))   [M=32768: grid 4x128]
  gemm8<2><<<512, 512, 0, stream>>>(Xb, W1b, b1, nullptr, Hb,
                                    1024, 1024, 0, 0, 0, 1.0f, 4, 512);
  // Fb = bf16(Hb @ W2^T + b2 + Xb)    (residual fused)
  gemm8<7><<<512, 512, 0, stream>>>(Hb, W2b, b2, Xb, Fb,
                                    1024, 1024, 0, 0, 0, 1.0f, 4, 512);
  // out = LN(Fb)  (fp32 final)
  ln_bf_kernel<<<4096, 512, 0, stream>>>(Fb, gamma, beta, out, nullptr);
}